// Round 7
// baseline (106.981 us; speedup 1.0000x reference)
//
#include <hip/hip_runtime.h>

// ---- types ----
typedef __attribute__((ext_vector_type(8))) short  bf16x8;  // 8 bf16 = 4 VGPR
typedef __attribute__((ext_vector_type(4))) float  f32x4;

static __device__ __forceinline__ unsigned short f2bf(float f) {
    unsigned u = __float_as_uint(f);
    u += 0x7fffu + ((u >> 16) & 1u);      // RNE (inputs are finite)
    return (unsigned short)(u >> 16);
}

// ---------------------------------------------------------------------------
// Prep: At[bn][n][k] = bf16(A[bn][k][n]); 32*128*128 bf16 = 1 MB into d_ws.
// ---------------------------------------------------------------------------
__global__ __launch_bounds__(256) void prep_at_kernel(
        const float* __restrict__ A, unsigned short* __restrict__ At)
{
    int g   = blockIdx.x * 256 + threadIdx.x;   // 65536 total
    int bn  = g >> 11;
    int rem = g & 2047;
    int kc  = rem >> 7;                         // k octet
    int n   = rem & 127;

    const float* src = A + bn * 16384 + kc * 8 * 128 + n;
    unsigned h[4];
    #pragma unroll
    for (int j = 0; j < 4; ++j) {
        unsigned short lo = f2bf(src[(2 * j    ) * 128]);
        unsigned short hi = f2bf(src[(2 * j + 1) * 128]);
        h[j] = (unsigned)lo | ((unsigned)hi << 16);
    }
    uint4 pk = make_uint4(h[0], h[1], h[2], h[3]);
    *(uint4*)(At + bn * 16384 + n * 128 + kc * 8) = pk;
}

// ---------------------------------------------------------------------------
// Main (R6 + dx-in-LDS so NO VMEM load is consumed inside the loop):
// R6 post-mortem: per-iter dx loads forced compiler vmcnt(0) at their use ->
// drained the staged tiles every iteration (in-order vmcnt). Now the loop's
// only VMEM = 2 global_load_lds + 8 stores; exact counted waits apply.
// Grid 512 = 32 bn x 16; 512 thr = 8 waves; wave (wm,wn) = 16 rows x 32 cols.
// At block -> regs once (bq[4][2]); dx rows for this block's 32 tiles (1024
// rows, 8 KB) -> LDS in prologue (read via ds_read -> lgkmcnt domain).
// v tile 32x128 f32, 3 LDS buffers (48 KB), depth-2 prefetch, XOR-swizzle
// (row&7)<<4 on pre-swizzled global source + swizzled LDS read (dest linear).
// Counted waits (in-order retirement arithmetic, ops/iter = 2 stage + 8 st):
//   iter 0: vmcnt(2)  keep S(1)            iter 1: vmcnt(10) keep stage(2)+st
//   iters 2..30: vmcnt(18) = st(k-1) 8 + stage(k+1) 2 + st(k-2) 8 -> S(k)
//   retired, S(k+1)/S(k+2) stay in flight  iter 31 (no stage): vmcnt(16)
// ---------------------------------------------------------------------------
__global__ __launch_bounds__(512, 4) void trans_main_kernel(
        const float* __restrict__ v,  const float* __restrict__ dx,
        const unsigned short* __restrict__ At, const float* __restrict__ Bm,
        const float* __restrict__ bsc, float* __restrict__ out)
{
    __shared__ float  lds[3][32 * 128];         // 48 KB
    __shared__ float2 dxl[1024];                // 8 KB

    const int tid = threadIdx.x;
    const int wid = tid >> 6;
    const int l   = tid & 63;
    const int lr  = l & 15;
    const int lq  = l >> 4;
    const int wm  = wid >> 2;                   // 0..1 (16-row half)
    const int wn  = wid & 3;                    // 0..3 (32-col quarter)
    const int bn     = blockIdx.x >> 4;         // 0..31
    const int mtbase = blockIdx.x & 15;         // 0..15

    // ---- At block -> registers, once. b-frag: B[k=lq*8+j][n=col] ----
    bf16x8 bq[4][2];
    const unsigned short* atb = At + bn * 16384 + (wn * 32 + lr) * 128 + lq * 8;
    #pragma unroll
    for (int kq = 0; kq < 4; ++kq)
        #pragma unroll
        for (int ni = 0; ni < 2; ++ni)
            bq[kq][ni] = *(const bf16x8*)(atb + ni * 16 * 128 + kq * 32);

    // ---- epilogue constants ----
    const float bias = *bsc;
    const int col0 = bn * 128 + wn * 32;
    float2 bc[2];
    #pragma unroll
    for (int ni = 0; ni < 2; ++ni)
        bc[ni] = *(const float2*)(Bm + 2 * (col0 + ni * 16 + lr));

    // ---- dx rows for this block's 32 tiles -> LDS (prologue only) ----
    #pragma unroll
    for (int it = 0; it < 2; ++it) {
        int idx  = it * 512 + tid;              // 0..1023
        int kk   = idx >> 5;                    // tile 0..31
        int r    = idx & 31;                    // row in tile
        int grow = (kk * 16 + mtbase) * 32 + r;
        dxl[idx] = *(const float2*)(dx + 2 * grow);
    }

    // ---- async stage of one 32x128 tile (pre-swizzled source) ----
    auto stage = [&](int buf, int k) {
        const float* src = v + (size_t)(k * 16 + mtbase) * 32 * 4096 + bn * 128;
        #pragma unroll
        for (int it = 0; it < 2; ++it) {
            int c16  = it * 512 + tid;          // 16B-chunk index (0..1023)
            int row  = c16 >> 5;                // 32 chunks per 512B row
            int off  = (c16 & 31) << 4;
            int soff = off ^ ((row & 7) << 4);  // inverse-swizzled source
            const float* g = src + (size_t)row * 4096 + (soff >> 2);
            __builtin_amdgcn_global_load_lds(
                (const __attribute__((address_space(1))) unsigned int*)g,
                (__attribute__((address_space(3))) unsigned int*)
                    &lds[buf][c16 * 4],
                16, 0, 0);
        }
    };

    // ---- compute + fused epilogue for tile k from buffer buf ----
    auto body = [&](int buf, int k) {
        const int mt = k * 16 + mtbase;
        f32x4 acc[2];
        acc[0] = (f32x4){0.f, 0.f, 0.f, 0.f};
        acc[1] = (f32x4){0.f, 0.f, 0.f, 0.f};

        const char* Lb = (const char*)&lds[buf][0];
        const int row = wm * 16 + lr;
        const int rb  = row * 512;
        const int m   = (row & 7) << 4;
        #pragma unroll
        for (int kq = 0; kq < 4; ++kq) {
            const int base = kq * 128 + lq * 32;
            float4 f0 = *(const float4*)(Lb + rb + ((base     ) ^ m));
            float4 f1 = *(const float4*)(Lb + rb + ((base + 16) ^ m));
            union { bf16x8 vv; unsigned short s[8]; } u;
            u.s[0] = f2bf(f0.x); u.s[1] = f2bf(f0.y);
            u.s[2] = f2bf(f0.z); u.s[3] = f2bf(f0.w);
            u.s[4] = f2bf(f1.x); u.s[5] = f2bf(f1.y);
            u.s[6] = f2bf(f1.z); u.s[7] = f2bf(f1.w);
            acc[0] = __builtin_amdgcn_mfma_f32_16x16x32_bf16(
                         u.vv, bq[kq][0], acc[0], 0, 0, 0);
            acc[1] = __builtin_amdgcn_mfma_f32_16x16x32_bf16(
                         u.vv, bq[kq][1], acc[1], 0, 0, 0);
        }

        #pragma unroll
        for (int jj = 0; jj < 4; ++jj) {
            const int rl   = k * 32 + wm * 16 + lq * 4 + jj;  // dxl index
            const int rowg = mt * 32 + wm * 16 + lq * 4 + jj;
            const float2 d = dxl[rl];                          // LDS read
            float* orow = out + (size_t)rowg * 4096 + col0 + lr;
            float v0 = acc[0][jj] + d.x * bc[0].x + d.y * bc[0].y + bias;
            float v1 = acc[1][jj] + d.x * bc[1].x + d.y * bc[1].y + bias;
            orow[0]  = fmaxf(v0, 0.0f);
            orow[16] = fmaxf(v1, 0.0f);
        }
    };

    __syncthreads();                            // dxl ready (drains all)

    // ---- pipeline: depth-2 prefetch, counted vmcnt, raw barriers ----
    stage(0, 0);
    stage(1, 1);

    // iter 0: keep S(1) in flight
    asm volatile("s_waitcnt vmcnt(2) lgkmcnt(0)" ::: "memory");
    __builtin_amdgcn_s_barrier();
    __builtin_amdgcn_sched_barrier(0);
    stage(2, 2);
    body(0, 0);

    // iter 1: newest 10 = st(0) 8 + stage(2) 2 -> S(1) retired
    asm volatile("s_waitcnt vmcnt(10) lgkmcnt(0)" ::: "memory");
    __builtin_amdgcn_s_barrier();
    __builtin_amdgcn_sched_barrier(0);
    stage(0, 3);
    body(1, 1);

    for (int k = 2; k < 31; ++k) {
        asm volatile("s_waitcnt vmcnt(18) lgkmcnt(0)" ::: "memory");
        __builtin_amdgcn_s_barrier();
        __builtin_amdgcn_sched_barrier(0);
        if (k + 2 < 32) stage((k + 2) % 3, k + 2);
        body(k % 3, k);
    }

    // iter 31 (no stage): newest 16 = st(30) 8 + st(29) 8 -> S(31) retired
    asm volatile("s_waitcnt vmcnt(16) lgkmcnt(0)" ::: "memory");
    __builtin_amdgcn_s_barrier();
    __builtin_amdgcn_sched_barrier(0);
    body(31 % 3, 31);
}

// ---------------------------------------------------------------------------
extern "C" void kernel_launch(void* const* d_in, const int* in_sizes, int n_in,
                              void* d_out, int out_size, void* d_ws, size_t ws_size,
                              hipStream_t stream)
{
    const float* v  = (const float*)d_in[0];   // [16384, 4096]
    const float* dx = (const float*)d_in[1];   // [16384, 2]
    const float* A  = (const float*)d_in[2];   // [32, 128, 128]
    const float* Bm = (const float*)d_in[3];   // [4096, 2]
    const float* b  = (const float*)d_in[4];   // scalar

    unsigned short* At = (unsigned short*)d_ws; // 1 MB: [32][128 n][128 k] bf16

    prep_at_kernel<<<dim3(256), dim3(256), 0, stream>>>(A, At);
    trans_main_kernel<<<dim3(512), dim3(512), 0, stream>>>(v, dx, At, Bm, b,
                                                           (float*)d_out);
}